// Round 5
// baseline (614.930 us; speedup 1.0000x reference)
//
#include <hip/hip_runtime.h>

// ConvLSTM2D fused fp16-MFMA implementation for MI355X (gfx950).
// B=8 T=16 H=W=256 C=3 F=36 K=5 stride4 VALID input conv; stride1 SAME recurrent.
// Ho=Wo=63, gates N=144 (permuted n' = fq*16 + g*4 + fr, f = fq*4+fr).
//
// Structure: one fused step kernel launched 16x. Block = 256 thr (4 waves,
// 2M x 2N), tile M=128 (= 2 output rows x 64 cols), N=144. grid 32x8 = 256
// blocks = 1/CU. NHWC im2col along (kw,c) is contiguous, so A-fragments are
// direct ds_reads from staged zero-haloed rows (h: A[x][k] = hrow[x*36+k],
// K=180 padded 192; x: A[x][k2] = xrow[x*12+k2], K=15 padded 32 via zeroed
// weight rows). Wh streamed through a double-buffered LDS half-tile with
// global_load_lds (wave-linear dest pattern; barrier vmcnt drain = handoff).
//
// Static model: LDS-BW-bound (~132KB/slice vs 291cyc MFMA); 2Mx2N is the
// duplication-minimal wave split (A-dup 2 x 24KB + B-dup 2 x 27KB + DMA 30KB).
// NOTE (audited, r3): per-pixel pitch padding 36->40 for b128 A-reads is
// INVALID — lane K-fragments cross kw boundaries and rely on pitch==C exactly.

typedef _Float16 f16;
typedef __attribute__((ext_vector_type(8))) _Float16 f16x8;
typedef __attribute__((ext_vector_type(4))) float f32x4;

#define TPB 256

// ---- LDS layout (bytes) ----
// h_sh : ushort[6*2412]          @ 0       (28944)   6 haloed h rows, pitch 67*36
// x_sh : ushort[9*788]           @ 28944   (14184->14192 pad) 9 input rows, pitch 788
// w2_sh: ushort[5*144*40]        @ 43136   (57600)   all Wx, [kh2][n'][40]
// w_sh : ushort[2][144*104]      @ 100736  (59904)   Wh half-tile double buffer
// z_sh : float[128*148]          @ 28944   (75776)   overlay (used after GEMM)
#define H_SH_OFF   0
#define X_SH_OFF   28944
#define W2_SH_OFF  43136
#define W_SH_OFF   100736
#define Z_SH_OFF   28944
#define LDS_BYTES  160640

#define WHP_GRAN_PER_SLICE 1872   // uint4 per (kh,half) Wh slice = 144*104*2/16
#define W_BUF_USH 14976           // 144*104

union Cv8 { ushort4 u4[2]; uint4 q; f16x8 h8; };
union Cvh { f16 h; ushort u; };
union Cv2 { f16 h[2]; uint u; };

__device__ inline f16x8 ld8_lds(const ushort* p) {   // 8B-aligned (2x ds_read_b64)
  Cv8 c; c.u4[0] = *(const ushort4*)p; c.u4[1] = *(const ushort4*)(p + 4);
  return c.h8;
}
__device__ inline f16x8 ld16_lds(const ushort* p) {  // 16B-aligned (ds_read_b128)
  Cv8 c; c.q = *(const uint4*)p; return c.h8;
}
__device__ inline ushort f2us(float v) { Cvh c; c.h = (f16)v; return c.u; }

// async global->LDS, 16B per lane; dest must be wave-uniform base + lane*16.
typedef const __attribute__((address_space(1))) uint guint;
typedef __attribute__((address_space(3))) uint luint;
__device__ inline void gload_lds16(const void* gp, void* lp) {
  __builtin_amdgcn_global_load_lds((guint*)gp, (luint*)lp, 16, 0, 0);
}

__device__ inline float tanh_fast(float x) {
  float e = __expf(2.f * x);                    // inf-safe: rcp(inf)=0 -> 1
  return 1.f - 2.f * __builtin_amdgcn_rcpf(e + 1.f);
}

// ---------------- weight prep: permute gates + pad + fp16 ----------------
// whp: [s=kh*2+hf][n'(144)][kk(104)] fp16, k = hf*96+kk, valid k<180 (=kw*36+c)
// wxp: [kh2(5)][n'(144)][kk2(40)] fp16, valid kk2<15 (=kw*3+cin)
// bperm: [n'] fp32
__global__ void prep_weights(const float* __restrict__ Wx, const float* __restrict__ Wh,
                             const float* __restrict__ bb,
                             ushort* __restrict__ whp, ushort* __restrict__ wxp,
                             float* __restrict__ bperm) {
  int i = blockIdx.x * 256 + threadIdx.x;
  if (i < 149760) {
    int kk = i % 104; int rest = i / 104;
    int np = rest % 144; int s = rest / 144;
    int kh = s >> 1, hf = s & 1;
    int k = hf * 96 + kk;
    float v = 0.f;
    if (kk < 96 && k < 180) {
      int kw = k / 36, c = k - kw * 36;
      int fq = np >> 4, g = (np >> 2) & 3, fr = np & 3;
      int n = g * 36 + fq * 4 + fr;
      v = Wh[(((kh * 5 + kw) * 36 + c) * 144) + n];
    }
    whp[i] = f2us(v);
  } else if (i < 178560) {
    int e = i - 149760;
    int kk2 = e % 40; int rest = e / 40;
    int np = rest % 144; int kh2 = rest / 144;
    float v = 0.f;
    if (kk2 < 15) {
      int kw = kk2 / 3, cin = kk2 - kw * 3;
      int fq = np >> 4, g = (np >> 2) & 3, fr = np & 3;
      int n = g * 36 + fq * 4 + fr;
      v = Wx[(((kh2 * 5 + kw) * 3 + cin) * 144) + n];
    }
    wxp[e] = f2us(v);
  } else if (i < 178704) {
    int np = i - 178560;
    int fq = np >> 4, g = (np >> 2) & 3, fr = np & 3;
    bperm[np] = bb[g * 36 + fq * 4 + fr];
  }
}

// ---------------- GEMM pieces (templated over N-frag share per wave) ----------------
// MFMA 16x16x32 f16 layout (m89/m91-verified family):
//   A[m][k]: m = lane&15, k = (lane>>4)*8 + j;  B[k][n]: n = lane&15, same k map.
//   D[m][n]: n = lane&15, m = (lane>>4)*4 + j   (dtype-independent, m121-m128).
template<int S, int FQ0>
__device__ void x_chunks(f32x4 (&acc)[4][5], const ushort* x_sh, const ushort* w2_sh,
                         int mh, int lane) {
  const int l16 = lane & 15, lg = lane >> 4;
#pragma unroll
  for (int kh2 = 0; kh2 < 5; ++kh2) {
    f16x8 a[4];
#pragma unroll
    for (int r = 0; r < 4; ++r)
      a[r] = ld8_lds(x_sh + (mh * 4 + kh2) * 788 + (r * 16 + l16) * 12 + lg * 8);
#pragma unroll
    for (int s = 0; s < S; ++s) {
      f16x8 bf = ld16_lds(w2_sh + (kh2 * 144 + (FQ0 + s) * 16 + l16) * 40 + lg * 8);
#pragma unroll
      for (int r = 0; r < 4; ++r)
        acc[r][s] = __builtin_amdgcn_mfma_f32_16x16x32_f16(a[r], bf, acc[r][s], 0, 0, 0);
    }
  }
}

template<int S, int FQ0>
__device__ void h_chunks(f32x4 (&acc)[4][5], const ushort* h_sh, const ushort* wbuf,
                         int kh, int hf, int mh, int lane) {
  const int l16 = lane & 15, lg = lane >> 4;
  const ushort* hrow = h_sh + (mh + kh) * 2412;
#pragma unroll
  for (int cc = 0; cc < 3; ++cc) {
    const int k0 = hf * 96 + cc * 32;
    f16x8 a[4];
    // NOTE: for hf=1,cc=2 the read k range is 160..191; k>=180 are zero-weight
    // pad. Offsets may run up to 48 ushorts past this hrow into the next staged
    // row (last row: into x_sh) — always staged finite data, so garbage*0 == 0.
#pragma unroll
    for (int r = 0; r < 4; ++r)
      a[r] = ld8_lds(hrow + (r * 16 + l16) * 36 + k0 + lg * 8);
#pragma unroll
    for (int s = 0; s < S; ++s) {
      f16x8 bf = ld16_lds(wbuf + ((FQ0 + s) * 16 + l16) * 104 + cc * 32 + lg * 8);
#pragma unroll
      for (int r = 0; r < 4; ++r)
        acc[r][s] = __builtin_amdgcn_mfma_f32_16x16x32_f16(a[r], bf, acc[r][s], 0, 0, 0);
    }
  }
}

template<int S, int FQ0>
__device__ void z_write(const f32x4 (&acc)[4][5], float* z_sh, int mh, int lane) {
  const int l16 = lane & 15, lg = lane >> 4;
#pragma unroll
  for (int r = 0; r < 4; ++r)
#pragma unroll
    for (int s = 0; s < S; ++s)
#pragma unroll
      for (int j = 0; j < 4; ++j)
        z_sh[(mh * 64 + r * 16 + lg * 4 + j) * 148 + (FQ0 + s) * 16 + l16] = acc[r][s][j];
}

__device__ inline void stage_wh_slice(const ushort* whp, int slice, ushort* dstbuf, int tid) {
  const uint4* src = (const uint4*)whp + (size_t)slice * WHP_GRAN_PER_SLICE;
#pragma unroll
  for (int k = 0; k < 8; ++k) {
    int g = tid + k * 256;
    if (g < WHP_GRAN_PER_SLICE)
      gload_lds16(src + g, (char*)dstbuf + (size_t)g * 16);
  }
}

// ---------------- fused per-timestep kernel ----------------
__global__ __launch_bounds__(TPB, 1)
void convlstm_step(const float* __restrict__ x_all, int t,
                   const f16* __restrict__ h_prev, f16* __restrict__ h_next,
                   float* __restrict__ c_st,
                   const ushort* __restrict__ whp, const ushort* __restrict__ wxp,
                   const float* __restrict__ bperm,
                   float* __restrict__ out, int flags) {
  extern __shared__ char smem[];
  ushort* h_sh  = (ushort*)(smem + H_SH_OFF);
  ushort* x_sh  = (ushort*)(smem + X_SH_OFF);
  ushort* w2_sh = (ushort*)(smem + W2_SH_OFF);
  ushort* w_sh  = (ushort*)(smem + W_SH_OFF);
  float*  z_sh  = (float*)(smem + Z_SH_OFF);

  const int tid = threadIdx.x;
  const int lane = tid & 63, wave = tid >> 6;
  const int mh = wave >> 1, nh = wave & 1;
  const int y0 = blockIdx.x * 2, b = blockIdx.y;
  const bool first = (flags & 1) != 0, last = (flags & 2) != 0;

  // ---- issue async weight DMA first (latency hides under x/h reg staging) ----
  {
    const uint4* src = (const uint4*)wxp;
#pragma unroll
    for (int k = 0; k < 15; ++k) {
      int g = tid + k * 256;
      if (g < 3600) gload_lds16(src + g, (char*)w2_sh + (size_t)g * 16);
    }
  }
  if (!first) stage_wh_slice(whp, 0, w_sh, tid);

  // ---- stage x rows (fp32 -> fp16 via float4), then zero 768..787 tail ----
  {
    const float* xrow0 = x_all + (size_t)(b * 16 + t) * 196608;
    uint* xs32 = (uint*)x_sh;
#pragma unroll
    for (int k = 0; k < 7; ++k) {
      int g = tid + k * 256;
      if (g < 1728) {
        int row = g / 192, e = g - row * 192;
        int yi = y0 * 4 + row;
        float4 v = make_float4(0.f, 0.f, 0.f, 0.f);
        if (yi < 256) v = *(const float4*)(xrow0 + yi * 768 + e * 4);
        Cv2 c0, c1;
        c0.h[0] = (f16)v.x; c0.h[1] = (f16)v.y;
        c1.h[0] = (f16)v.z; c1.h[1] = (f16)v.w;
        xs32[row * 394 + e * 2]     = c0.u;
        xs32[row * 394 + e * 2 + 1] = c1.u;
      }
    }
    if (tid < 90) {
      int row = tid / 10, u = 384 + (tid - (tid / 10) * 10);
      xs32[row * 394 + u] = 0;
    }
  }
  // ---- stage h rows (fp16, zero halo), uint2 granules ----
  if (!first) {
    const uint2* src = (const uint2*)h_prev;
    uint2* hs = (uint2*)h_sh;
#pragma unroll
    for (int k = 0; k < 15; ++k) {
      int g = tid + k * 256;
      if (g < 3618) {
        int row = g / 603, u2 = g - row * 603;
        int hy = y0 - 2 + row;
        uint2 val = make_uint2(0, 0);
        if (hy >= 0 && hy < 63 && u2 >= 18 && u2 < 585)
          val = src[(size_t)(b * 63 + hy) * 567 + (u2 - 18)];
        hs[g] = val;
      }
    }
  }
  __syncthreads();  // implicit vmcnt(0) drain: DMA'd Wx + Wh slice 0 landed

  f32x4 acc[4][5];
#pragma unroll
  for (int r = 0; r < 4; ++r)
#pragma unroll
    for (int s = 0; s < 5; ++s) acc[r][s] = (f32x4)(0.f);

  // ---- input-conv chunks (K=5x32, zero-padded weights) ----
  if (nh == 0) x_chunks<5, 0>(acc, x_sh, w2_sh, mh, lane);
  else         x_chunks<4, 5>(acc, x_sh, w2_sh, mh, lane);

  // ---- recurrent-conv: 10 half-tiles (kh x 2), double-buffered Wh DMA ----
  if (!first) {
#pragma unroll 1
    for (int s = 0; s < 10; ++s) {
      if (s < 9)  // DMA next slice into the idle buffer; barrier drain = handoff
        stage_wh_slice(whp, s + 1, w_sh + ((s + 1) & 1) * W_BUF_USH, tid);
      const ushort* wbuf = w_sh + (s & 1) * W_BUF_USH;
      if (nh == 0) h_chunks<5, 0>(acc, h_sh, wbuf, s >> 1, s & 1, mh, lane);
      else         h_chunks<4, 5>(acc, h_sh, wbuf, s >> 1, s & 1, mh, lane);
      __syncthreads();
    }
  }

  // ---- z tile to LDS (overlays x/w2/w-buf0; all prior reads barrier-complete,
  //      last buf0 DMA drained at s=7's barrier, last buf0 read fenced at s=8) ----
  __syncthreads();
  if (nh == 0) z_write<5, 0>(acc, z_sh, mh, lane);
  else         z_write<4, 5>(acc, z_sh, mh, lane);
  __syncthreads();

  // ---- gates + state update ----
#pragma unroll 1
  for (int it = 0; it < 18; ++it) {
    int u = tid + it * 256;                 // 18*256 == 128*36 exactly
    int x_sub = u / 36, f = u - x_sub * 36;
    int x = x_sub & 63, y = y0 + (x_sub >> 6);
    if (x < 63 && y < 63) {
      int cb = (f >> 2) * 16 + (f & 3);
      const float* zr = z_sh + x_sub * 148;
      float zi = zr[cb]      + bperm[cb];
      float zf = zr[cb + 4]  + bperm[cb + 4];
      float zc = zr[cb + 8]  + bperm[cb + 8];
      float zo = zr[cb + 12] + bperm[cb + 12];
      float gi = fminf(fmaxf(0.2f * zi + 0.5f, 0.f), 1.f);
      float gf = fminf(fmaxf(0.2f * zf + 0.5f, 0.f), 1.f);
      float go = fminf(fmaxf(0.2f * zo + 0.5f, 0.f), 1.f);
      float tc = tanh_fast(zc);
      size_t idx = (size_t)((b * 63 + y) * 63 + x) * 36 + f;
      float cold = first ? 0.f : c_st[idx];
      float cn = gf * cold + gi * tc;
      float hn = go * tanh_fast(cn);
      c_st[idx] = cn;
      h_next[idx] = (f16)hn;
      if (last) out[(size_t)b * 142884 + ((y * 63 + x) * 36 + f)] = hn;
    }
  }
}

// ---------------- host launcher ----------------
extern "C" void kernel_launch(void* const* d_in, const int* in_sizes, int n_in,
                              void* d_out, int out_size, void* d_ws, size_t ws_size,
                              hipStream_t stream) {
  (void)in_sizes; (void)n_in; (void)out_size; (void)ws_size;
  const float* states = (const float*)d_in[0];
  const float* Wx = (const float*)d_in[1];
  const float* Wh = (const float*)d_in[2];
  const float* bb = (const float*)d_in[3];
  float* out = (float*)d_out;
  char* ws = (char*)d_ws;

  ushort* whp   = (ushort*)(ws + 0);        // 299520 B
  ushort* wxp   = (ushort*)(ws + 299520);   // 57600 B
  float*  bperm = (float*)(ws + 357120);    // 576 B
  f16*    hb0   = (f16*)(ws + 357696);      // 2286144 B
  f16*    hb1   = (f16*)(ws + 2643840);     // 2286144 B
  float*  c_st  = (float*)(ws + 4929984);   // 4572288 B  (total ~9.5 MB)

  hipFuncSetAttribute((const void*)convlstm_step,
                      hipFuncAttributeMaxDynamicSharedMemorySize, LDS_BYTES);

  prep_weights<<<699, 256, 0, stream>>>(Wx, Wh, bb, whp, wxp, bperm);
  for (int t = 0; t < 16; ++t) {
    int flags = (t == 0 ? 1 : 0) | (t == 15 ? 2 : 0);
    f16* hp = (t & 1) ? hb1 : hb0;
    f16* hn = (t & 1) ? hb0 : hb1;
    convlstm_step<<<dim3(32, 8), TPB, LDS_BYTES, stream>>>(
        states, t, hp, hn, c_st, whp, wxp, bperm, out, flags);
  }
}